// Round 12
// baseline (1475.977 us; speedup 1.0000x reference)
//
#include <hip/hip_runtime.h>
#include <hip/hip_bf16.h>

typedef __attribute__((ext_vector_type(8))) short bfrag8;
typedef __attribute__((ext_vector_type(4))) float f32x4;

#define DEV static __device__ __forceinline__

constexpr int B_ = 512, T_ = 256, I_ = 256, H_ = 256;
constexpr int GROUPS = 8, BPG = 32, ROWS = 64, JPB = 8;
constexpr int NTHR = 512;
constexpr int DEPTH = 4;    // h ring depth
constexpr int ARRT = 128;   // per-step arrival target: 4 waves x 32 blocks
constexpr size_t XBF_GSTRIDE = (size_t)2 * ROWS * T_ * H_;  // bf16 elems (16 MB)

DEV unsigned short f2bf(float f) {
  __hip_bfloat16 h = __float2bfloat16(f);
  return *reinterpret_cast<unsigned short*>(&h);
}
DEV float bf2f(unsigned short u) {
  __hip_bfloat16 h;
  *reinterpret_cast<unsigned short*>(&h) = u;
  return __bfloat162float(h);
}
DEV float sigm(float x) { return 1.0f / (1.0f + __expf(-x)); }
DEV float tanh_f(float x) {
  float e = __expf(-2.0f * fabsf(x));
  float t = (1.0f - e) / (1.0f + e);
  return copysignf(t, x);
}
DEV bfrag8 cvt_frag(const float* p) {
  float4 a = *reinterpret_cast<const float4*>(p);
  float4 b = *reinterpret_cast<const float4*>(p + 4);
  bfrag8 r;
  r[0] = (short)f2bf(a.x); r[1] = (short)f2bf(a.y);
  r[2] = (short)f2bf(a.z); r[3] = (short)f2bf(a.w);
  r[4] = (short)f2bf(b.x); r[5] = (short)f2bf(b.y);
  r[6] = (short)f2bf(b.z); r[7] = (short)f2bf(b.w);
  return r;
}

// ---- device-coherent (LLC) access helpers: proven R2..R10 ----
DEV void ld_hfrag(const void* p, uint4& a0, uint4& a1, uint4& a2, uint4& a3,
                  uint4& a4, uint4& a5, uint4& a6, uint4& a7) {
  asm volatile(
      "global_load_dwordx4 %0, %8, off sc0 sc1\n\t"
      "global_load_dwordx4 %1, %8, off offset:64 sc0 sc1\n\t"
      "global_load_dwordx4 %2, %8, off offset:128 sc0 sc1\n\t"
      "global_load_dwordx4 %3, %8, off offset:192 sc0 sc1\n\t"
      "global_load_dwordx4 %4, %8, off offset:256 sc0 sc1\n\t"
      "global_load_dwordx4 %5, %8, off offset:320 sc0 sc1\n\t"
      "global_load_dwordx4 %6, %8, off offset:384 sc0 sc1\n\t"
      "global_load_dwordx4 %7, %8, off offset:448 sc0 sc1\n\t"
      "s_waitcnt vmcnt(0)"
      : "=&v"(a0), "=&v"(a1), "=&v"(a2), "=&v"(a3),
        "=&v"(a4), "=&v"(a5), "=&v"(a6), "=&v"(a7)
      : "v"(p)
      : "memory");
}
DEV uint2 ld_sys_8B(const void* p) {
  uint2 r;
  asm volatile("global_load_dwordx2 %0, %1, off sc0 sc1\n\ts_waitcnt vmcnt(0)"
               : "=&v"(r) : "v"(p) : "memory");
  return r;
}
DEV void st_sys_u16(unsigned short* p, unsigned int v) {
  asm volatile("global_store_short %0, %1, off sc0 sc1" :: "v"(p), "v"(v) : "memory");
}
DEV void st_sys_u32(unsigned int* p, unsigned int v) {
  asm volatile("global_store_dword %0, %1, off sc0 sc1" :: "v"(p), "v"(v) : "memory");
}
DEV void drain_vm() { asm volatile("s_waitcnt vmcnt(0)" ::: "memory"); }
DEV void arriveN(int* p, int n) {
  __hip_atomic_fetch_add(p, n, __ATOMIC_RELAXED, __HIP_MEMORY_SCOPE_SYSTEM);
}
DEV int poll(const int* p) {
  return __hip_atomic_load(p, __ATOMIC_RELAXED, __HIP_MEMORY_SCOPE_SYSTEM);
}

// ---- prepass: x f32 -> bf16, group-local layout inside group's o2 slice ----
__global__ __launch_bounds__(256) void cvt_x_group(const float* __restrict__ x,
                                                   unsigned short* __restrict__ xbf) {
  int b = blockIdx.x;
  int g = b >> 6, rl = b & 63;
  const float* src = x + (size_t)b * T_ * I_;
  unsigned short* dst = xbf + (size_t)g * XBF_GSTRIDE + (size_t)rl * T_ * I_;
  for (int i = threadIdx.x * 8; i < T_ * I_; i += 256 * 8) {
    float4 a = *reinterpret_cast<const float4*>(src + i);
    float4 c = *reinterpret_cast<const float4*>(src + i + 4);
    ushort4 p, q;
    p.x = f2bf(a.x); p.y = f2bf(a.y); p.z = f2bf(a.z); p.w = f2bf(a.w);
    q.x = f2bf(c.x); q.y = f2bf(c.y); q.z = f2bf(c.z); q.w = f2bf(c.w);
    *reinterpret_cast<ushort4*>(dst + i) = p;
    *reinterpret_cast<ushort4*>(dst + i + 4) = q;
  }
}

__global__ __launch_bounds__(NTHR, 2) void lstm_fused(
    const float* __restrict__ x, const unsigned short* __restrict__ x_bf,
    const int* __restrict__ is_init,
    const float* __restrict__ hx, const float* __restrict__ cx,
    const float* __restrict__ W_ih, const float* __restrict__ W_hh,
    const float* __restrict__ b_ih, const float* __restrict__ b_hh,
    const float* __restrict__ ln_w, const float* __restrict__ ln_b,
    float* __restrict__ out,
    unsigned short* __restrict__ hbuf, float* __restrict__ cts,
    int* __restrict__ cntg) {
  extern __shared__ char occupancy_pad[];          // 80 KB pad -> 1 block/CU
  __shared__ unsigned short wfr[2 * 16 * 64 * 8];  // W fragments, 32 KB
  __shared__ f32x4 xacc[2][4][64][2];              // x-projection handoff, 16 KB
  __shared__ float biasl[32];

  const int tid = threadIdx.x;
  const int g = blockIdx.x & 7;
  const int mem = blockIdx.x >> 3;   // member 0..31 within group
  const int rowbase = g * ROWS;
  const int jbase = mem * JPB;

  unsigned short* hb = hbuf + g * (DEPTH * ROWS * H_);
  int* cnt = cntg + g * 512;
  const unsigned short* xbg = x_bf + (size_t)g * XBF_GSTRIDE;  // [rl][t][i]

  const int wv = tid >> 6;            // 0..7
  const int lane = tid & 63;
  const int c = lane & 15;            // col-in-half 0..15
  const int kq = lane >> 4;           // k sub-chunk / row-quad 0..3
  const int mt = wv & 3;              // M-tile (recurrence: wv, helper: wv-4)
  const int arow = mt * 16 + c;       // A-frag batch row (local)
  const int jl = c & 7;               // hidden col (local)
  const int selhi = c >> 3;           // 0: rows +0,1 ; 1: rows +2,3
  const int rowA = mt * 16 + kq * 4 + selhi * 2;  // pointwise row A (local)
  const int rowB = rowA + 1;
  const int jcol = jbase + jl;

  float4 lnw4 = *reinterpret_cast<const float4*>(ln_w + lane * 4);
  float4 lnb4 = *reinterpret_cast<const float4*>(ln_b + lane * 4);

  // W fragment macro: (mat, m, nth) -> bf16x8, lane-consecutive 16B
#define WFRAG(mat, m, nth) (*reinterpret_cast<const bfrag8*>( \
    &wfr[(((mat) * 16 + (m) * 2 + (nth)) * 64 + lane) * 8]))

  // ---- prologue: stage W fragments into LDS (validated R5..R10 mapping) ----
  {
#pragma unroll
    for (int i2 = 0; i2 < 4; ++i2) {
      int fid = tid * 4 + i2;
      int lp = fid & 63;
      int m = (fid >> 6) & 7;
      int ntp = (fid >> 9) & 1;
      int mat = fid >> 10;
      int nn = ntp * 16 + (lp & 15);
      int kqp = lp >> 4;
      int growp = (nn >> 3) * 256 + jbase + (nn & 7);
      const float* src = (mat ? W_hh : W_ih) + growp * 256 + m * 32 + kqp * 8;
      *reinterpret_cast<bfrag8*>(&wfr[((mat * 16 + m * 2 + ntp) * 64 + lp) * 8]) =
          cvt_frag(src);
    }
  }
  if (tid < 32) {
    int gr2 = (tid >> 3) * 256 + jbase + (tid & 7);
    biasl[tid] = b_ih[gr2] + b_hh[gr2];
  }
  // per-lane biases for pointwise (4 gates of jcol)
  float bi = b_ih[0 * 256 + jcol] + b_hh[0 * 256 + jcol];
  float bf = b_ih[1 * 256 + jcol] + b_hh[1 * 256 + jcol];
  float bg = b_ih[2 * 256 + jcol] + b_hh[2 * 256 + jcol];
  float bo = b_ih[3 * 256 + jcol] + b_hh[3 * 256 + jcol];
  {  // publish h_{-1} = hx into ring slot 3
    int r = tid >> 8, cc = tid & 255;
    int lr = 2 * mem + r;
    st_sys_u16(hb + 3 * ROWS * H_ + lr * H_ + cc,
               (unsigned int)f2bf(hx[(size_t)(rowbase + lr) * H_ + cc]));
  }
  // recurrence cell state (2 rows per lane)
  float cregA = cx[(size_t)(rowbase + rowA) * H_ + jcol];
  float cregB = cx[(size_t)(rowbase + rowB) * H_ + jcol];
  drain_vm();
  __syncthreads();
  if (tid == 0) arriveN(&cnt[0], 4);  // whole-block h_{-1} drained -> weight 4

  // helpers: xacc(0) = x_0 . W_ih (wfr staged pre-barrier)
  if (wv >= 4) {
    const unsigned short* xb = xbg + ((size_t)arow * T_ + 0) * I_ + kq * 8;
    f32x4 a0 = {0.f, 0.f, 0.f, 0.f}, a1 = {0.f, 0.f, 0.f, 0.f};
#pragma unroll
    for (int m = 0; m < 8; ++m) {
      bfrag8 xf = *reinterpret_cast<const bfrag8*>(xb + m * 32);
      a0 = __builtin_amdgcn_mfma_f32_16x16x32_bf16(xf, WFRAG(0, m, 0), a0, 0, 0, 0);
      a1 = __builtin_amdgcn_mfma_f32_16x16x32_bf16(xf, WFRAG(0, m, 1), a1, 0, 0, 0);
    }
    xacc[0][mt][lane][0] = a0;
    xacc[0][mt][lane][1] = a1;
  }

  // ---- main loop over time ----
  for (int t = 0; t < T_; ++t) {
    // per-wave pre-issue (no barriers inside)
    int iiA = 0, iiPA = 0, iiPB = 0;
    bfrag8 xf[8];
    float4 xskip;
    if (wv < 4) {
      iiA = is_init[(size_t)(rowbase + arow) * T_ + t];
      iiPA = is_init[(size_t)(rowbase + rowA) * T_ + t];
      iiPB = is_init[(size_t)(rowbase + rowB) * T_ + t];
    } else {
      int tn = (t + 1 < T_) ? t + 1 : t;
      const unsigned short* xb = xbg + ((size_t)arow * T_ + tn) * I_ + kq * 8;
#pragma unroll
      for (int m = 0; m < 8; ++m)
        xf[m] = *reinterpret_cast<const bfrag8*>(xb + m * 32);
      if (t > 0 && wv < 6) {
        int gr = rowbase + 2 * mem + (wv - 4);
        xskip = *reinterpret_cast<const float4*>(
            x + ((size_t)gr * T_ + (t - 1)) * I_ + lane * 4);
      }
    }

    // (B) wait until all 128 wave-arrivals for h_{t-1}
    if (tid == 0) {
      while (poll(&cnt[t]) < ARRT) __builtin_amdgcn_s_sleep(1);
    }
    __syncthreads();  // S1 (also the xacc handoff fence)

    const unsigned short* hbr = hb + ((t + 3) & 3) * (ROWS * H_);

    if (wv < 4) {
      // ---- recurrence critical path ----
      uint4 h0, h1, h2, h3, h4, h5, h6, h7;
      ld_hfrag(hbr + arow * H_ + kq * 8, h0, h1, h2, h3, h4, h5, h6, h7);
      unsigned km = iiA ? 0u : 0xffffffffu;
#define MASK4(v) v.x &= km; v.y &= km; v.z &= km; v.w &= km
      MASK4(h0); MASK4(h1); MASK4(h2); MASK4(h3);
      MASK4(h4); MASK4(h5); MASK4(h6); MASK4(h7);
#undef MASK4
      f32x4 acc0 = xacc[t & 1][mt][lane][0];
      f32x4 acc1 = xacc[t & 1][mt][lane][1];
#define HM(v, m) \
      acc0 = __builtin_amdgcn_mfma_f32_16x16x32_bf16(__builtin_bit_cast(bfrag8, v), WFRAG(1, m, 0), acc0, 0, 0, 0); \
      acc1 = __builtin_amdgcn_mfma_f32_16x16x32_bf16(__builtin_bit_cast(bfrag8, v), WFRAG(1, m, 1), acc1, 0, 0, 0)
      HM(h0, 0); HM(h1, 1); HM(h2, 2); HM(h3, 3);
      HM(h4, 4); HM(h5, 5); HM(h6, 6); HM(h7, 7);
#undef HM
      // gate exchange: partner lane (c^8) holds the other two gates
      f32x4 po0, po1;
#pragma unroll
      for (int r = 0; r < 4; ++r) {
        po0[r] = __shfl_xor(acc0[r], 8);
        po1[r] = __shfl_xor(acc1[r], 8);
      }
      float iA, iB, fA, fB, gA, gB, oA, oB;
      if (selhi == 0) {
        iA = acc0[0]; iB = acc0[1]; gA = acc1[0]; gB = acc1[1];
        fA = po0[0];  fB = po0[1];  oA = po1[0];  oB = po1[1];
      } else {
        fA = acc0[2]; fB = acc0[3]; oA = acc1[2]; oB = acc1[3];
        iA = po0[2];  iB = po0[3];  gA = po1[2];  gB = po1[3];
      }
      unsigned short* hbw = hb + (t & 3) * (ROWS * H_);
      {
        float ig = sigm(iA + bi), fg = sigm(fA + bf);
        float gg = tanh_f(gA + bg), og = sigm(oA + bo);
        float rm = iiPA ? 0.f : 1.f;
        cregA = fg * (cregA * rm) + ig * gg;
        st_sys_u16(hbw + rowA * H_ + jcol, (unsigned int)f2bf(og * tanh_f(cregA)));
      }
      {
        float ig = sigm(iB + bi), fg = sigm(fB + bf);
        float gg = tanh_f(gB + bg), og = sigm(oB + bo);
        float rm = iiPB ? 0.f : 1.f;
        cregB = fg * (cregB * rm) + ig * gg;
        st_sys_u16(hbw + rowB * H_ + jcol, (unsigned int)f2bf(og * tanh_f(cregB)));
      }
      drain_vm();  // own stores at LLC
      if (lane == 0) arriveN(&cnt[t + 1], 1);  // per-wave arrival (no barrier)
    } else {
      // ---- helpers: xacc(t+1) + LN(t-1) ----
      if (t + 1 < T_) {
        f32x4 a0 = {0.f, 0.f, 0.f, 0.f}, a1 = {0.f, 0.f, 0.f, 0.f};
#pragma unroll
        for (int m = 0; m < 8; ++m) {
          a0 = __builtin_amdgcn_mfma_f32_16x16x32_bf16(xf[m], WFRAG(0, m, 0), a0, 0, 0, 0);
          a1 = __builtin_amdgcn_mfma_f32_16x16x32_bf16(xf[m], WFRAG(0, m, 1), a1, 0, 0, 0);
        }
        xacc[(t + 1) & 1][mt][lane][0] = a0;
        xacc[(t + 1) & 1][mt][lane][1] = a1;
      }
      if (t > 0 && wv < 6) {  // LN(t-1) + x skip, rows 2*mem, 2*mem+1
        int lr = 2 * mem + (wv - 4);
        int gr = rowbase + lr;
        uint2 hv = ld_sys_8B(hbr + lr * H_ + lane * 4);
        float h0v = bf2f((unsigned short)(hv.x & 0xffff));
        float h1v = bf2f((unsigned short)(hv.x >> 16));
        float h2v = bf2f((unsigned short)(hv.y & 0xffff));
        float h3v = bf2f((unsigned short)(hv.y >> 16));
        float s = h0v + h1v + h2v + h3v;
        float q = h0v * h0v + h1v * h1v + h2v * h2v + h3v * h3v;
#pragma unroll
        for (int m = 1; m < 64; m <<= 1) {
          s += __shfl_xor(s, m);
          q += __shfl_xor(q, m);
        }
        float mu = s * (1.0f / 256.0f);
        float var = q * (1.0f / 256.0f) - mu * mu;
        float rs = rsqrtf(var + 1e-5f);
        float4 o4;
        o4.x = (h0v - mu) * rs * lnw4.x + lnb4.x + xskip.x;
        o4.y = (h1v - mu) * rs * lnw4.y + lnb4.y + xskip.y;
        o4.z = (h2v - mu) * rs * lnw4.z + lnb4.z + xskip.z;
        o4.w = (h3v - mu) * rs * lnw4.w + lnb4.w + xskip.w;
        *reinterpret_cast<float4*>(out + ((size_t)gr * T_ + (t - 1)) * H_ + lane * 4) = o4;
      }
    }
  }

  // ---- epilogue ----
  if (tid == 0) {
    while (poll(&cnt[T_]) < ARRT) __builtin_amdgcn_s_sleep(1);
  }
  __syncthreads();
  const unsigned short* hT = hb + ((T_ - 1) & 3) * (ROWS * H_);
  // LN for timestep T-1 (proven R6/R9/R10 path)
  if (wv < 2) {
    int lr = 2 * mem + wv;
    int gr = rowbase + lr;
    uint2 hv = ld_sys_8B(hT + lr * H_ + lane * 4);
    float h0v = bf2f((unsigned short)(hv.x & 0xffff));
    float h1v = bf2f((unsigned short)(hv.x >> 16));
    float h2v = bf2f((unsigned short)(hv.y & 0xffff));
    float h3v = bf2f((unsigned short)(hv.y >> 16));
    float s = h0v + h1v + h2v + h3v;
    float q = h0v * h0v + h1v * h1v + h2v * h2v + h3v * h3v;
#pragma unroll
    for (int m = 1; m < 64; m <<= 1) {
      s += __shfl_xor(s, m);
      q += __shfl_xor(q, m);
    }
    float mu = s * (1.0f / 256.0f);
    float var = q * (1.0f / 256.0f) - mu * mu;
    float rs = rsqrtf(var + 1e-5f);
    const float* xp = x + ((size_t)gr * T_ + (T_ - 1)) * I_ + lane * 4;
    float4 xv = *reinterpret_cast<const float4*>(xp);
    float4 o4;
    o4.x = (h0v - mu) * rs * lnw4.x + lnb4.x + xv.x;
    o4.y = (h1v - mu) * rs * lnw4.y + lnb4.y + xv.y;
    o4.z = (h2v - mu) * rs * lnw4.z + lnb4.z + xv.z;
    o4.w = (h3v - mu) * rs * lnw4.w + lnb4.w + xv.w;
    *reinterpret_cast<float4*>(out + ((size_t)gr * T_ + (T_ - 1)) * H_ + lane * 4) = o4;
  }
  if (wv < 4) {  // final cell state
    st_sys_u32(reinterpret_cast<unsigned int*>(
                   cts + (size_t)(rowbase + rowA) * H_ + jcol),
               __float_as_uint(cregA));
    st_sys_u32(reinterpret_cast<unsigned int*>(
                   cts + (size_t)(rowbase + rowB) * H_ + jcol),
               __float_as_uint(cregB));
  }
  drain_vm();
  __syncthreads();
  if (tid == 0) {
    arriveN(&cnt[T_ + 1], 1);
    while (poll(&cnt[T_ + 1]) < BPG) __builtin_amdgcn_s_sleep(1);
  }
  __syncthreads();
  {  // broadcast hT, cT over the T axis (own 2 rows; coalesced writes)
    int r = tid >> 8;
    int lr = 2 * mem + r;
    int gr = rowbase + lr;
    int c4 = (tid & 63) * 4;
    int tph = (tid >> 6) & 3;
    uint2 hu = ld_sys_8B(hT + lr * H_ + c4);
    float4 hv;
    hv.x = bf2f((unsigned short)(hu.x & 0xffff));
    hv.y = bf2f((unsigned short)(hu.x >> 16));
    hv.z = bf2f((unsigned short)(hu.y & 0xffff));
    hv.w = bf2f((unsigned short)(hu.y >> 16));
    uint2 ca = ld_sys_8B(cts + (size_t)gr * H_ + c4);
    uint2 cb = ld_sys_8B(cts + (size_t)gr * H_ + c4 + 2);
    float4 cv;
    cv.x = __uint_as_float(ca.x); cv.y = __uint_as_float(ca.y);
    cv.z = __uint_as_float(cb.x); cv.w = __uint_as_float(cb.y);
    float* o1 = out + (size_t)B_ * T_ * H_ + (size_t)gr * T_ * H_;
    float* o2 = o1 + (size_t)B_ * T_ * H_;
    for (int tt = tph; tt < T_; tt += 4) {
      *reinterpret_cast<float4*>(o1 + tt * H_ + c4) = hv;
      *reinterpret_cast<float4*>(o2 + tt * H_ + c4) = cv;
    }
  }
#undef WFRAG
}

extern "C" void kernel_launch(void* const* d_in, const int* in_sizes, int n_in,
                              void* d_out, int out_size, void* d_ws, size_t ws_size,
                              hipStream_t stream) {
  (void)in_sizes; (void)n_in; (void)out_size; (void)ws_size;
  const float* x = (const float*)d_in[0];
  const int* is_init = (const int*)d_in[1];
  const float* hx = (const float*)d_in[2];
  const float* cx = (const float*)d_in[3];
  const float* W_ih = (const float*)d_in[4];
  const float* W_hh = (const float*)d_in[5];
  const float* b_ih = (const float*)d_in[6];
  const float* b_hh = (const float*)d_in[7];
  const float* ln_w = (const float*)d_in[8];
  const float* ln_b = (const float*)d_in[9];
  float* out = (float*)d_out;

  char* ws = (char*)d_ws;
  unsigned short* hbuf = (unsigned short*)ws;          // 1 MB
  float* cts = (float*)(ws + (1 << 20));               // 512 KB
  int* cnt = (int*)(ws + (1 << 20) + (512 << 10));     // 8 * 512 ints

  // x_bf inside each group's OWN o2 output slice (16 MB stride; first 8 MB).
  unsigned short* x_bf = (unsigned short*)(out + 2ull * B_ * T_ * H_);

  cvt_x_group<<<dim3(B_), dim3(256), 0, stream>>>(x, x_bf);
  hipMemsetAsync(cnt, 0, GROUPS * 512 * sizeof(int), stream);
  // ~49 KB static LDS + 80 KB pad -> 1 block/CU, 256 blocks resident.
  lstm_fused<<<dim3(GROUPS * BPG), dim3(NTHR), 81920, stream>>>(
      x, x_bf, is_init, hx, cx, W_ih, W_hh, b_ih, b_hh, ln_w, ln_b, out,
      hbuf, cts, cnt);
}

// Round 14
// 995.549 us; speedup vs baseline: 1.4826x; 1.4826x over previous
//
#include <hip/hip_runtime.h>
#include <hip/hip_bf16.h>

typedef __attribute__((ext_vector_type(8))) short bfrag8;
typedef __attribute__((ext_vector_type(4))) float f32x4;

#define DEV static __device__ __forceinline__

constexpr int B_ = 512, T_ = 256, I_ = 256, H_ = 256;
constexpr int GROUPS = 8, BPG = 32, ROWS = 64, JPB = 8;
constexpr int NTHR = 512;
constexpr int DEPTH = 4;     // h ring depth
constexpr int NSH = 8;       // counter shards per group (4 blocks each)
constexpr int SHST = 520;    // shard stride in ints (2080 B -> distinct lines)
constexpr size_t XBF_GSTRIDE = (size_t)2 * ROWS * T_ * H_;  // bf16 elems (16 MB)

DEV unsigned short f2bf(float f) {
  __hip_bfloat16 h = __float2bfloat16(f);
  return *reinterpret_cast<unsigned short*>(&h);
}
DEV float bf2f(unsigned short u) {
  __hip_bfloat16 h;
  *reinterpret_cast<unsigned short*>(&h) = u;
  return __bfloat162float(h);
}
DEV float sigm(float x) { return 1.0f / (1.0f + __expf(-x)); }
DEV float tanh_f(float x) {
  float e = __expf(-2.0f * fabsf(x));
  float t = (1.0f - e) / (1.0f + e);
  return copysignf(t, x);
}
DEV bfrag8 cvt_frag(const float* p) {
  float4 a = *reinterpret_cast<const float4*>(p);
  float4 b = *reinterpret_cast<const float4*>(p + 4);
  bfrag8 r;
  r[0] = (short)f2bf(a.x); r[1] = (short)f2bf(a.y);
  r[2] = (short)f2bf(a.z); r[3] = (short)f2bf(a.w);
  r[4] = (short)f2bf(b.x); r[5] = (short)f2bf(b.y);
  r[6] = (short)f2bf(b.z); r[7] = (short)f2bf(b.w);
  return r;
}

// ---- device-coherent (LLC) access helpers: proven R2..R10 ----
DEV void ld_hfrag(const void* p, uint4& a0, uint4& a1, uint4& a2, uint4& a3,
                  uint4& a4, uint4& a5, uint4& a6, uint4& a7) {
  asm volatile(
      "global_load_dwordx4 %0, %8, off sc0 sc1\n\t"
      "global_load_dwordx4 %1, %8, off offset:64 sc0 sc1\n\t"
      "global_load_dwordx4 %2, %8, off offset:128 sc0 sc1\n\t"
      "global_load_dwordx4 %3, %8, off offset:192 sc0 sc1\n\t"
      "global_load_dwordx4 %4, %8, off offset:256 sc0 sc1\n\t"
      "global_load_dwordx4 %5, %8, off offset:320 sc0 sc1\n\t"
      "global_load_dwordx4 %6, %8, off offset:384 sc0 sc1\n\t"
      "global_load_dwordx4 %7, %8, off offset:448 sc0 sc1\n\t"
      "s_waitcnt vmcnt(0)"
      : "=&v"(a0), "=&v"(a1), "=&v"(a2), "=&v"(a3),
        "=&v"(a4), "=&v"(a5), "=&v"(a6), "=&v"(a7)
      : "v"(p)
      : "memory");
}
DEV uint2 ld_sys_8B(const void* p) {
  uint2 r;
  asm volatile("global_load_dwordx2 %0, %1, off sc0 sc1\n\ts_waitcnt vmcnt(0)"
               : "=&v"(r) : "v"(p) : "memory");
  return r;
}
DEV void st_sys_u16(unsigned short* p, unsigned int v) {
  asm volatile("global_store_short %0, %1, off sc0 sc1" :: "v"(p), "v"(v) : "memory");
}
DEV void st_sys_u32(unsigned int* p, unsigned int v) {
  asm volatile("global_store_dword %0, %1, off sc0 sc1" :: "v"(p), "v"(v) : "memory");
}
DEV void drain_vm() { asm volatile("s_waitcnt vmcnt(0)" ::: "memory"); }
DEV void arriveN(int* p, int n) {
  __hip_atomic_fetch_add(p, n, __ATOMIC_RELAXED, __HIP_MEMORY_SCOPE_SYSTEM);
}
DEV int poll(const int* p) {
  return __hip_atomic_load(p, __ATOMIC_RELAXED, __HIP_MEMORY_SCOPE_SYSTEM);
}

// ---- prepass: x f32 -> bf16, group-local layout inside group's o2 slice ----
__global__ __launch_bounds__(256) void cvt_x_group(const float* __restrict__ x,
                                                   unsigned short* __restrict__ xbf) {
  int b = blockIdx.x;
  int g = b >> 6, rl = b & 63;
  const float* src = x + (size_t)b * T_ * I_;
  unsigned short* dst = xbf + (size_t)g * XBF_GSTRIDE + (size_t)rl * T_ * I_;
  for (int i = threadIdx.x * 8; i < T_ * I_; i += 256 * 8) {
    float4 a = *reinterpret_cast<const float4*>(src + i);
    float4 c = *reinterpret_cast<const float4*>(src + i + 4);
    ushort4 p, q;
    p.x = f2bf(a.x); p.y = f2bf(a.y); p.z = f2bf(a.z); p.w = f2bf(a.w);
    q.x = f2bf(c.x); q.y = f2bf(c.y); q.z = f2bf(c.z); q.w = f2bf(c.w);
    *reinterpret_cast<ushort4*>(dst + i) = p;
    *reinterpret_cast<ushort4*>(dst + i + 4) = q;
  }
}

__global__ __launch_bounds__(NTHR, 2) void lstm_fused(
    const float* __restrict__ x, const unsigned short* __restrict__ x_bf,
    const int* __restrict__ is_init,
    const float* __restrict__ hx, const float* __restrict__ cx,
    const float* __restrict__ W_ih, const float* __restrict__ W_hh,
    const float* __restrict__ b_ih, const float* __restrict__ b_hh,
    const float* __restrict__ ln_w, const float* __restrict__ ln_b,
    float* __restrict__ out,
    unsigned short* __restrict__ hbuf, float* __restrict__ cts,
    int* __restrict__ cntg) {
  extern __shared__ char occupancy_pad[];          // 80 KB pad -> 1 block/CU
  __shared__ unsigned short wfr[2 * 16 * 64 * 8];  // W fragments, 32 KB
  __shared__ f32x4 xacc[2][4][64][2];              // x-projection handoff, 16 KB
  __shared__ float biasl[32];

  const int tid = threadIdx.x;
  const int g = blockIdx.x & 7;
  const int mem = blockIdx.x >> 3;   // member 0..31 within group
  const int rowbase = g * ROWS;
  const int jbase = mem * JPB;

  unsigned short* hb = hbuf + g * (DEPTH * ROWS * H_);
  int* cnt = cntg + g * (NSH * SHST);        // 8 shard rows of 520 ints
  int* myshard = cnt + (mem & (NSH - 1)) * SHST;  // this block's arrival row

  const int wv = tid >> 6;            // 0..7
  const int lane = tid & 63;
  const int c = lane & 15;            // col-in-half 0..15
  const int kq = lane >> 4;           // k sub-chunk / row-quad 0..3
  const int mt = wv & 3;              // M-tile (recurrence: wv, helper: wv-4)
  const int arow = mt * 16 + c;       // A-frag batch row (local)
  const int jl = c & 7;               // hidden col (local)
  const int selhi = c >> 3;           // 0: rows +0,1 ; 1: rows +2,3
  const int rowA = mt * 16 + kq * 4 + selhi * 2;  // pointwise row A (local)
  const int rowB = rowA + 1;
  const int jcol = jbase + jl;

  float4 lnw4 = *reinterpret_cast<const float4*>(ln_w + lane * 4);
  float4 lnb4 = *reinterpret_cast<const float4*>(ln_b + lane * 4);

  // sharded poll: wave 0; every lane loads shard (lane&7)'s counter for step
  // `tstep`; proceed when all 8 shards show 4 arrivals.
  auto poll_all = [&](int tstep) {
    // caller guarantees wv == 0
    const int* pp = cnt + (lane & (NSH - 1)) * SHST + tstep;
    while (true) {
      int v = poll(pp);
      if (__all(v >= 4)) break;
      __builtin_amdgcn_s_sleep(1);
    }
  };

  // W fragment macro: (mat, m, nth) -> bf16x8, lane-consecutive 16B
#define WFRAG(mat, m, nth) (*reinterpret_cast<const bfrag8*>( \
    &wfr[(((mat) * 16 + (m) * 2 + (nth)) * 64 + lane) * 8]))

  // ---- prologue: stage W fragments into LDS (validated R5..R10 mapping) ----
  {
#pragma unroll
    for (int i2 = 0; i2 < 4; ++i2) {
      int fid = tid * 4 + i2;
      int lp = fid & 63;
      int m = (fid >> 6) & 7;
      int ntp = (fid >> 9) & 1;
      int mat = fid >> 10;
      int nn = ntp * 16 + (lp & 15);
      int kqp = lp >> 4;
      int growp = (nn >> 3) * 256 + jbase + (nn & 7);
      const float* src = (mat ? W_hh : W_ih) + growp * 256 + m * 32 + kqp * 8;
      *reinterpret_cast<bfrag8*>(&wfr[((mat * 16 + m * 2 + ntp) * 64 + lp) * 8]) =
          cvt_frag(src);
    }
  }
  if (tid < 32) {
    int gr2 = (tid >> 3) * 256 + jbase + (tid & 7);
    biasl[tid] = b_ih[gr2] + b_hh[gr2];
  }
  // per-lane biases for pointwise (4 gates of jcol)
  float bi = b_ih[0 * 256 + jcol] + b_hh[0 * 256 + jcol];
  float bf = b_ih[1 * 256 + jcol] + b_hh[1 * 256 + jcol];
  float bg = b_ih[2 * 256 + jcol] + b_hh[2 * 256 + jcol];
  float bo = b_ih[3 * 256 + jcol] + b_hh[3 * 256 + jcol];
  {  // publish h_{-1} = hx into ring slot 3
    int r = tid >> 8, cc = tid & 255;
    int lr = 2 * mem + r;
    st_sys_u16(hb + 3 * ROWS * H_ + lr * H_ + cc,
               (unsigned int)f2bf(hx[(size_t)(rowbase + lr) * H_ + cc]));
  }
  // recurrence cell state (2 rows per lane)
  float cregA = cx[(size_t)(rowbase + rowA) * H_ + jcol];
  float cregB = cx[(size_t)(rowbase + rowB) * H_ + jcol];
  drain_vm();
  __syncthreads();
  if (tid == 0) arriveN(&myshard[0], 1);  // h_{-1} drained (atomic, R10-proven)

  // helpers: xacc(0) = x_0 . W_ih (wfr staged pre-barrier)
  const unsigned short* xbg = x_bf + (size_t)g * XBF_GSTRIDE;  // [rl][t][i]
  if (wv >= 4) {
    const unsigned short* xb = xbg + ((size_t)arow * T_ + 0) * I_ + kq * 8;
    f32x4 a0 = {0.f, 0.f, 0.f, 0.f}, a1 = {0.f, 0.f, 0.f, 0.f};
#pragma unroll
    for (int m = 0; m < 8; ++m) {
      bfrag8 xf = *reinterpret_cast<const bfrag8*>(xb + m * 32);
      a0 = __builtin_amdgcn_mfma_f32_16x16x32_bf16(xf, WFRAG(0, m, 0), a0, 0, 0, 0);
      a1 = __builtin_amdgcn_mfma_f32_16x16x32_bf16(xf, WFRAG(0, m, 1), a1, 0, 0, 0);
    }
    xacc[0][mt][lane][0] = a0;
    xacc[0][mt][lane][1] = a1;
  }

  // ---- main loop over time ----
  for (int t = 0; t < T_; ++t) {
    // per-wave pre-issue (no barriers inside)
    int iiA = 0, iiPA = 0, iiPB = 0;
    bfrag8 xf[8];
    float4 xskip;
    if (wv < 4) {
      iiA = is_init[(size_t)(rowbase + arow) * T_ + t];
      iiPA = is_init[(size_t)(rowbase + rowA) * T_ + t];
      iiPB = is_init[(size_t)(rowbase + rowB) * T_ + t];
    } else {
      int tn = (t + 1 < T_) ? t + 1 : t;
      const unsigned short* xb = xbg + ((size_t)arow * T_ + tn) * I_ + kq * 8;
#pragma unroll
      for (int m = 0; m < 8; ++m)
        xf[m] = *reinterpret_cast<const bfrag8*>(xb + m * 32);
      if (t > 0 && wv < 6) {
        int gr = rowbase + 2 * mem + (wv - 4);
        xskip = *reinterpret_cast<const float4*>(
            x + ((size_t)gr * T_ + (t - 1)) * I_ + lane * 4);
      }
    }

    // (B) wait until all 8 shards show 4 arrivals for h_{t-1}
    if (wv == 0) poll_all(t);
    __syncthreads();  // S1 (also the xacc handoff fence)

    const unsigned short* hbr = hb + ((t + 3) & 3) * (ROWS * H_);

    if (wv < 4) {
      // ---- recurrence critical path ----
      uint4 h0, h1, h2, h3, h4, h5, h6, h7;
      ld_hfrag(hbr + arow * H_ + kq * 8, h0, h1, h2, h3, h4, h5, h6, h7);
      unsigned km = iiA ? 0u : 0xffffffffu;
#define MASK4(v) v.x &= km; v.y &= km; v.z &= km; v.w &= km
      MASK4(h0); MASK4(h1); MASK4(h2); MASK4(h3);
      MASK4(h4); MASK4(h5); MASK4(h6); MASK4(h7);
#undef MASK4
      f32x4 acc0 = xacc[t & 1][mt][lane][0];
      f32x4 acc1 = xacc[t & 1][mt][lane][1];
#define HM(v, m) \
      acc0 = __builtin_amdgcn_mfma_f32_16x16x32_bf16(__builtin_bit_cast(bfrag8, v), WFRAG(1, m, 0), acc0, 0, 0, 0); \
      acc1 = __builtin_amdgcn_mfma_f32_16x16x32_bf16(__builtin_bit_cast(bfrag8, v), WFRAG(1, m, 1), acc1, 0, 0, 0)
      HM(h0, 0); HM(h1, 1); HM(h2, 2); HM(h3, 3);
      HM(h4, 4); HM(h5, 5); HM(h6, 6); HM(h7, 7);
#undef HM
      // gate exchange: partner lane (c^8) holds the other two gates
      f32x4 po0, po1;
#pragma unroll
      for (int r = 0; r < 4; ++r) {
        po0[r] = __shfl_xor(acc0[r], 8);
        po1[r] = __shfl_xor(acc1[r], 8);
      }
      float iA, iB, fA, fB, gA, gB, oA, oB;
      if (selhi == 0) {
        iA = acc0[0]; iB = acc0[1]; gA = acc1[0]; gB = acc1[1];
        fA = po0[0];  fB = po0[1];  oA = po1[0];  oB = po1[1];
      } else {
        fA = acc0[2]; fB = acc0[3]; oA = acc1[2]; oB = acc1[3];
        iA = po0[2];  iB = po0[3];  gA = po1[2];  gB = po1[3];
      }
      unsigned short* hbw = hb + (t & 3) * (ROWS * H_);
      {
        float ig = sigm(iA + bi), fg = sigm(fA + bf);
        float gg = tanh_f(gA + bg), og = sigm(oA + bo);
        float rm = iiPA ? 0.f : 1.f;
        cregA = fg * (cregA * rm) + ig * gg;
        st_sys_u16(hbw + rowA * H_ + jcol, (unsigned int)f2bf(og * tanh_f(cregA)));
      }
      {
        float ig = sigm(iB + bi), fg = sigm(fB + bf);
        float gg = tanh_f(gB + bg), og = sigm(oB + bo);
        float rm = iiPB ? 0.f : 1.f;
        cregB = fg * (cregB * rm) + ig * gg;
        st_sys_u16(hbw + rowB * H_ + jcol, (unsigned int)f2bf(og * tanh_f(cregB)));
      }
      drain_vm();
    } else {
      // ---- helpers: xacc(t+1) + LN(t-1) ----
      if (t + 1 < T_) {
        f32x4 a0 = {0.f, 0.f, 0.f, 0.f}, a1 = {0.f, 0.f, 0.f, 0.f};
#pragma unroll
        for (int m = 0; m < 8; ++m) {
          a0 = __builtin_amdgcn_mfma_f32_16x16x32_bf16(xf[m], WFRAG(0, m, 0), a0, 0, 0, 0);
          a1 = __builtin_amdgcn_mfma_f32_16x16x32_bf16(xf[m], WFRAG(0, m, 1), a1, 0, 0, 0);
        }
        xacc[(t + 1) & 1][mt][lane][0] = a0;
        xacc[(t + 1) & 1][mt][lane][1] = a1;
      }
      if (t > 0 && wv < 6) {  // LN(t-1) + x skip, rows 2*mem, 2*mem+1
        int lr = 2 * mem + (wv - 4);
        int gr = rowbase + lr;
        uint2 hv = ld_sys_8B(hbr + lr * H_ + lane * 4);
        float h0v = bf2f((unsigned short)(hv.x & 0xffff));
        float h1v = bf2f((unsigned short)(hv.x >> 16));
        float h2v = bf2f((unsigned short)(hv.y & 0xffff));
        float h3v = bf2f((unsigned short)(hv.y >> 16));
        float s = h0v + h1v + h2v + h3v;
        float q = h0v * h0v + h1v * h1v + h2v * h2v + h3v * h3v;
#pragma unroll
        for (int m = 1; m < 64; m <<= 1) {
          s += __shfl_xor(s, m);
          q += __shfl_xor(q, m);
        }
        float mu = s * (1.0f / 256.0f);
        float var = q * (1.0f / 256.0f) - mu * mu;
        float rs = rsqrtf(var + 1e-5f);
        float4 o4;
        o4.x = (h0v - mu) * rs * lnw4.x + lnb4.x + xskip.x;
        o4.y = (h1v - mu) * rs * lnw4.y + lnb4.y + xskip.y;
        o4.z = (h2v - mu) * rs * lnw4.z + lnb4.z + xskip.z;
        o4.w = (h3v - mu) * rs * lnw4.w + lnb4.w + xskip.w;
        *reinterpret_cast<float4*>(out + ((size_t)gr * T_ + (t - 1)) * H_ + lane * 4) = o4;
      }
    }
    __syncthreads();  // S2: all recurrence stores drained block-wide
    if (tid == 0) arriveN(&myshard[t + 1], 1);  // atomic arrival (R10-proven)
  }

  // ---- epilogue ----
  if (wv == 0) poll_all(T_);
  __syncthreads();
  const unsigned short* hT = hb + ((T_ - 1) & 3) * (ROWS * H_);
  // LN for timestep T-1 (proven R6/R9/R10 path)
  if (wv < 2) {
    int lr = 2 * mem + wv;
    int gr = rowbase + lr;
    uint2 hv = ld_sys_8B(hT + lr * H_ + lane * 4);
    float h0v = bf2f((unsigned short)(hv.x & 0xffff));
    float h1v = bf2f((unsigned short)(hv.x >> 16));
    float h2v = bf2f((unsigned short)(hv.y & 0xffff));
    float h3v = bf2f((unsigned short)(hv.y >> 16));
    float s = h0v + h1v + h2v + h3v;
    float q = h0v * h0v + h1v * h1v + h2v * h2v + h3v * h3v;
#pragma unroll
    for (int m = 1; m < 64; m <<= 1) {
      s += __shfl_xor(s, m);
      q += __shfl_xor(q, m);
    }
    float mu = s * (1.0f / 256.0f);
    float var = q * (1.0f / 256.0f) - mu * mu;
    float rs = rsqrtf(var + 1e-5f);
    const float* xp = x + ((size_t)gr * T_ + (T_ - 1)) * I_ + lane * 4;
    float4 xv = *reinterpret_cast<const float4*>(xp);
    float4 o4;
    o4.x = (h0v - mu) * rs * lnw4.x + lnb4.x + xv.x;
    o4.y = (h1v - mu) * rs * lnw4.y + lnb4.y + xv.y;
    o4.z = (h2v - mu) * rs * lnw4.z + lnb4.z + xv.z;
    o4.w = (h3v - mu) * rs * lnw4.w + lnb4.w + xv.w;
    *reinterpret_cast<float4*>(out + ((size_t)gr * T_ + (T_ - 1)) * H_ + lane * 4) = o4;
  }
  if (wv < 4) {  // final cell state
    st_sys_u32(reinterpret_cast<unsigned int*>(
                   cts + (size_t)(rowbase + rowA) * H_ + jcol),
               __float_as_uint(cregA));
    st_sys_u32(reinterpret_cast<unsigned int*>(
                   cts + (size_t)(rowbase + rowB) * H_ + jcol),
               __float_as_uint(cregB));
  }
  drain_vm();
  __syncthreads();
  if (tid == 0) arriveN(&myshard[T_ + 1], 1);  // cts drained
  if (wv == 0) poll_all(T_ + 1);
  __syncthreads();
  {  // broadcast hT, cT over the T axis (own 2 rows; coalesced writes)
    int r = tid >> 8;
    int lr = 2 * mem + r;
    int gr = rowbase + lr;
    int c4 = (tid & 63) * 4;
    int tph = (tid >> 6) & 3;
    uint2 hu = ld_sys_8B(hT + lr * H_ + c4);
    float4 hv;
    hv.x = bf2f((unsigned short)(hu.x & 0xffff));
    hv.y = bf2f((unsigned short)(hu.x >> 16));
    hv.z = bf2f((unsigned short)(hu.y & 0xffff));
    hv.w = bf2f((unsigned short)(hu.y >> 16));
    uint2 ca = ld_sys_8B(cts + (size_t)gr * H_ + c4);
    uint2 cb = ld_sys_8B(cts + (size_t)gr * H_ + c4 + 2);
    float4 cv;
    cv.x = __uint_as_float(ca.x); cv.y = __uint_as_float(ca.y);
    cv.z = __uint_as_float(cb.x); cv.w = __uint_as_float(cb.y);
    float* o1 = out + (size_t)B_ * T_ * H_ + (size_t)gr * T_ * H_;
    float* o2 = o1 + (size_t)B_ * T_ * H_;
    for (int tt = tph; tt < T_; tt += 4) {
      *reinterpret_cast<float4*>(o1 + tt * H_ + c4) = hv;
      *reinterpret_cast<float4*>(o2 + tt * H_ + c4) = cv;
    }
  }
#undef WFRAG
}

extern "C" void kernel_launch(void* const* d_in, const int* in_sizes, int n_in,
                              void* d_out, int out_size, void* d_ws, size_t ws_size,
                              hipStream_t stream) {
  (void)in_sizes; (void)n_in; (void)out_size; (void)ws_size;
  const float* x = (const float*)d_in[0];
  const int* is_init = (const int*)d_in[1];
  const float* hx = (const float*)d_in[2];
  const float* cx = (const float*)d_in[3];
  const float* W_ih = (const float*)d_in[4];
  const float* W_hh = (const float*)d_in[5];
  const float* b_ih = (const float*)d_in[6];
  const float* b_hh = (const float*)d_in[7];
  const float* ln_w = (const float*)d_in[8];
  const float* ln_b = (const float*)d_in[9];
  float* out = (float*)d_out;

  char* ws = (char*)d_ws;
  unsigned short* hbuf = (unsigned short*)ws;          // 1 MB
  float* cts = (float*)(ws + (1 << 20));               // 512 KB
  int* cnt = (int*)(ws + (1 << 20) + (512 << 10));     // 8g * 8sh * 520 ints = 133 KB

  // x_bf inside each group's OWN o2 output slice (16 MB stride; first 8 MB).
  unsigned short* x_bf = (unsigned short*)(out + 2ull * B_ * T_ * H_);

  cvt_x_group<<<dim3(B_), dim3(256), 0, stream>>>(x, x_bf);
  hipMemsetAsync(cnt, 0, GROUPS * NSH * SHST * sizeof(int), stream);
  // ~49 KB static LDS + 80 KB pad -> 1 block/CU, 256 blocks resident.
  lstm_fused<<<dim3(GROUPS * BPG), dim3(NTHR), 81920, stream>>>(
      x, x_bf, is_init, hx, cx, W_ih, W_hh, b_ih, b_hh, ln_w, ln_b, out,
      hbuf, cts, cnt);
}

// Round 16
// 995.202 us; speedup vs baseline: 1.4831x; 1.0003x over previous
//
#include <hip/hip_runtime.h>
#include <hip/hip_bf16.h>

typedef __attribute__((ext_vector_type(8))) short bfrag8;
typedef __attribute__((ext_vector_type(4))) float f32x4;

#define DEV static __device__ __forceinline__

constexpr int B_ = 512, T_ = 256, I_ = 256, H_ = 256;
constexpr int GROUPS = 8, BPG = 32, ROWS = 64, JPB = 8;
constexpr int NTHR = 512;
constexpr int DEPTH = 4;     // h ring depth
constexpr int NSH = 8;       // counter shards per group (4 blocks each)
constexpr int SHST = 520;    // shard stride in ints (2080 B -> distinct lines)
constexpr size_t XBF_GSTRIDE = (size_t)2 * ROWS * T_ * H_;  // bf16 elems (16 MB)

DEV unsigned short f2bf(float f) {
  __hip_bfloat16 h = __float2bfloat16(f);
  return *reinterpret_cast<unsigned short*>(&h);
}
DEV float bf2f(unsigned short u) {
  __hip_bfloat16 h;
  *reinterpret_cast<unsigned short*>(&h) = u;
  return __bfloat162float(h);
}
DEV float sigm(float x) { return 1.0f / (1.0f + __expf(-x)); }
DEV float tanh_f(float x) {
  float e = __expf(-2.0f * fabsf(x));
  float t = (1.0f - e) / (1.0f + e);
  return copysignf(t, x);
}
DEV bfrag8 cvt_frag(const float* p) {
  float4 a = *reinterpret_cast<const float4*>(p);
  float4 b = *reinterpret_cast<const float4*>(p + 4);
  bfrag8 r;
  r[0] = (short)f2bf(a.x); r[1] = (short)f2bf(a.y);
  r[2] = (short)f2bf(a.z); r[3] = (short)f2bf(a.w);
  r[4] = (short)f2bf(b.x); r[5] = (short)f2bf(b.y);
  r[6] = (short)f2bf(b.z); r[7] = (short)f2bf(b.w);
  return r;
}

// ---- device-coherent (LLC) access helpers: proven R2..R14 ----
DEV void ld_hfrag(const void* p, uint4& a0, uint4& a1, uint4& a2, uint4& a3,
                  uint4& a4, uint4& a5, uint4& a6, uint4& a7) {
  asm volatile(
      "global_load_dwordx4 %0, %8, off sc0 sc1\n\t"
      "global_load_dwordx4 %1, %8, off offset:64 sc0 sc1\n\t"
      "global_load_dwordx4 %2, %8, off offset:128 sc0 sc1\n\t"
      "global_load_dwordx4 %3, %8, off offset:192 sc0 sc1\n\t"
      "global_load_dwordx4 %4, %8, off offset:256 sc0 sc1\n\t"
      "global_load_dwordx4 %5, %8, off offset:320 sc0 sc1\n\t"
      "global_load_dwordx4 %6, %8, off offset:384 sc0 sc1\n\t"
      "global_load_dwordx4 %7, %8, off offset:448 sc0 sc1\n\t"
      "s_waitcnt vmcnt(0)"
      : "=&v"(a0), "=&v"(a1), "=&v"(a2), "=&v"(a3),
        "=&v"(a4), "=&v"(a5), "=&v"(a6), "=&v"(a7)
      : "v"(p)
      : "memory");
}
DEV uint2 ld_sys_8B(const void* p) {
  uint2 r;
  asm volatile("global_load_dwordx2 %0, %1, off sc0 sc1\n\ts_waitcnt vmcnt(0)"
               : "=&v"(r) : "v"(p) : "memory");
  return r;
}
DEV void st_sys_u16(unsigned short* p, unsigned int v) {
  asm volatile("global_store_short %0, %1, off sc0 sc1" :: "v"(p), "v"(v) : "memory");
}
DEV void st_sys_u32(unsigned int* p, unsigned int v) {
  asm volatile("global_store_dword %0, %1, off sc0 sc1" :: "v"(p), "v"(v) : "memory");
}
DEV void drain_vm() { asm volatile("s_waitcnt vmcnt(0)" ::: "memory"); }
DEV void arriveN(int* p, int n) {
  __hip_atomic_fetch_add(p, n, __ATOMIC_RELAXED, __HIP_MEMORY_SCOPE_SYSTEM);
}
DEV int poll(const int* p) {
  return __hip_atomic_load(p, __ATOMIC_RELAXED, __HIP_MEMORY_SCOPE_SYSTEM);
}

// ---- prepass: x f32 -> bf16, group-local layout inside group's o2 slice ----
__global__ __launch_bounds__(256) void cvt_x_group(const float* __restrict__ x,
                                                   unsigned short* __restrict__ xbf) {
  int b = blockIdx.x;
  int g = b >> 6, rl = b & 63;
  const float* src = x + (size_t)b * T_ * I_;
  unsigned short* dst = xbf + (size_t)g * XBF_GSTRIDE + (size_t)rl * T_ * I_;
  for (int i = threadIdx.x * 8; i < T_ * I_; i += 256 * 8) {
    float4 a = *reinterpret_cast<const float4*>(src + i);
    float4 c = *reinterpret_cast<const float4*>(src + i + 4);
    ushort4 p, q;
    p.x = f2bf(a.x); p.y = f2bf(a.y); p.z = f2bf(a.z); p.w = f2bf(a.w);
    q.x = f2bf(c.x); q.y = f2bf(c.y); q.z = f2bf(c.z); q.w = f2bf(c.w);
    *reinterpret_cast<ushort4*>(dst + i) = p;
    *reinterpret_cast<ushort4*>(dst + i + 4) = q;
  }
}

__global__ __launch_bounds__(NTHR, 2) void lstm_fused(
    const float* __restrict__ x, const unsigned short* __restrict__ x_bf,
    const int* __restrict__ is_init,
    const float* __restrict__ hx, const float* __restrict__ cx,
    const float* __restrict__ W_ih, const float* __restrict__ W_hh,
    const float* __restrict__ b_ih, const float* __restrict__ b_hh,
    const float* __restrict__ ln_w, const float* __restrict__ ln_b,
    float* __restrict__ out,
    unsigned short* __restrict__ hbuf, float* __restrict__ cts,
    int* __restrict__ cntg) {
  extern __shared__ char occupancy_pad[];          // 80 KB pad -> 1 block/CU
  __shared__ unsigned short wfr[2 * 16 * 64 * 8];  // W fragments, 32 KB
  __shared__ f32x4 xacc[2][4][64][2];              // x-projection handoff, 16 KB
  __shared__ float biasl[32];

  const int tid = threadIdx.x;
  const int g = blockIdx.x & 7;
  const int mem = blockIdx.x >> 3;   // member 0..31 within group
  const int rowbase = g * ROWS;
  const int jbase = mem * JPB;

  unsigned short* hb = hbuf + g * (DEPTH * ROWS * H_);
  int* cnt = cntg + g * (NSH * SHST);        // 8 shard rows of 520 ints
  int* myshard = cnt + (mem & (NSH - 1)) * SHST;  // this block's arrival row

  const int wv = tid >> 6;            // 0..7
  const int lane = tid & 63;
  const int c = lane & 15;            // col-in-half 0..15
  const int kq = lane >> 4;           // k sub-chunk / row-quad 0..3
  const int mt = wv & 3;              // M-tile (recurrence: wv, helper: wv-4)
  const int arow = mt * 16 + c;       // A-frag batch row (local)
  const int jl = c & 7;               // hidden col (local)
  const int selhi = c >> 3;           // 0: rows +0,1 ; 1: rows +2,3
  const int rowA = mt * 16 + kq * 4 + selhi * 2;  // pointwise row A (local)
  const int rowB = rowA + 1;
  const int jcol = jbase + jl;

  float4 lnw4 = *reinterpret_cast<const float4*>(ln_w + lane * 4);
  float4 lnb4 = *reinterpret_cast<const float4*>(ln_b + lane * 4);

  // sharded poll: wave 0; every lane loads shard (lane&7)'s counter for step
  // `tstep`; proceed when all 8 shards show 4 arrivals.
  auto poll_all = [&](int tstep) {
    // caller guarantees wv == 0
    const int* pp = cnt + (lane & (NSH - 1)) * SHST + tstep;
    while (true) {
      int v = poll(pp);
      if (__all(v >= 4)) break;
      __builtin_amdgcn_s_sleep(1);
    }
  };

  // W fragment macro: (mat, m, nth) -> bf16x8, lane-consecutive 16B
#define WFRAG(mat, m, nth) (*reinterpret_cast<const bfrag8*>( \
    &wfr[(((mat) * 16 + (m) * 2 + (nth)) * 64 + lane) * 8]))

  // ---- prologue: stage W fragments into LDS (validated R5..R14 mapping) ----
  {
#pragma unroll
    for (int i2 = 0; i2 < 4; ++i2) {
      int fid = tid * 4 + i2;
      int lp = fid & 63;
      int m = (fid >> 6) & 7;
      int ntp = (fid >> 9) & 1;
      int mat = fid >> 10;
      int nn = ntp * 16 + (lp & 15);
      int kqp = lp >> 4;
      int growp = (nn >> 3) * 256 + jbase + (nn & 7);
      const float* src = (mat ? W_hh : W_ih) + growp * 256 + m * 32 + kqp * 8;
      *reinterpret_cast<bfrag8*>(&wfr[((mat * 16 + m * 2 + ntp) * 64 + lp) * 8]) =
          cvt_frag(src);
    }
  }
  if (tid < 32) {
    int gr2 = (tid >> 3) * 256 + jbase + (tid & 7);
    biasl[tid] = b_ih[gr2] + b_hh[gr2];
  }
  // per-lane biases for pointwise (4 gates of jcol)
  float bi = b_ih[0 * 256 + jcol] + b_hh[0 * 256 + jcol];
  float bf = b_ih[1 * 256 + jcol] + b_hh[1 * 256 + jcol];
  float bg = b_ih[2 * 256 + jcol] + b_hh[2 * 256 + jcol];
  float bo = b_ih[3 * 256 + jcol] + b_hh[3 * 256 + jcol];
  {  // publish h_{-1} = hx into ring slot 3
    int r = tid >> 8, cc = tid & 255;
    int lr = 2 * mem + r;
    st_sys_u16(hb + 3 * ROWS * H_ + lr * H_ + cc,
               (unsigned int)f2bf(hx[(size_t)(rowbase + lr) * H_ + cc]));
  }
  // recurrence cell state (2 rows per lane)
  float cregA = cx[(size_t)(rowbase + rowA) * H_ + jcol];
  float cregB = cx[(size_t)(rowbase + rowB) * H_ + jcol];
  drain_vm();
  __syncthreads();
  if (tid == 0) arriveN(&myshard[0], 1);  // h_{-1} drained (atomic, R10-proven)

  // helpers: xacc(0) = x_0 . W_ih (wfr staged pre-barrier)
  const unsigned short* xbg = x_bf + (size_t)g * XBF_GSTRIDE;  // [rl][t][i]
  if (wv >= 4) {
    const unsigned short* xb = xbg + ((size_t)arow * T_ + 0) * I_ + kq * 8;
    f32x4 a0 = {0.f, 0.f, 0.f, 0.f}, a1 = {0.f, 0.f, 0.f, 0.f};
#pragma unroll
    for (int m = 0; m < 8; ++m) {
      bfrag8 xf = *reinterpret_cast<const bfrag8*>(xb + m * 32);
      a0 = __builtin_amdgcn_mfma_f32_16x16x32_bf16(xf, WFRAG(0, m, 0), a0, 0, 0, 0);
      a1 = __builtin_amdgcn_mfma_f32_16x16x32_bf16(xf, WFRAG(0, m, 1), a1, 0, 0, 0);
    }
    xacc[0][mt][lane][0] = a0;
    xacc[0][mt][lane][1] = a1;
  }

  // ---- main loop over time ----
  for (int t = 0; t < T_; ++t) {
    // per-wave pre-issue (no barriers inside)
    int iiA = 0, iiPA = 0, iiPB = 0;
    bfrag8 xf[8];
    float4 xskip;
    if (wv < 4) {
      iiA = is_init[(size_t)(rowbase + arow) * T_ + t];
      iiPA = is_init[(size_t)(rowbase + rowA) * T_ + t];
      iiPB = is_init[(size_t)(rowbase + rowB) * T_ + t];
    } else {
      int tn = (t + 1 < T_) ? t + 1 : t;
      const unsigned short* xb = xbg + ((size_t)arow * T_ + tn) * I_ + kq * 8;
#pragma unroll
      for (int m = 0; m < 8; ++m)
        xf[m] = *reinterpret_cast<const bfrag8*>(xb + m * 32);
      if (t > 0 && wv < 6) {
        int gr = rowbase + 2 * mem + (wv - 4);
        xskip = *reinterpret_cast<const float4*>(
            x + ((size_t)gr * T_ + (t - 1)) * I_ + lane * 4);
      }
    }

    // (B) wait until all 8 shards show 4 arrivals for h_{t-1}
    if (wv == 0) poll_all(t);
    __syncthreads();  // S1 (also the xacc handoff fence)

    const unsigned short* hbr = hb + ((t + 3) & 3) * (ROWS * H_);

    if (wv < 4) {
      // ---- recurrence critical path ----
      uint4 h0, h1, h2, h3, h4, h5, h6, h7;
      ld_hfrag(hbr + arow * H_ + kq * 8, h0, h1, h2, h3, h4, h5, h6, h7);
      unsigned km = iiA ? 0u : 0xffffffffu;
#define MASK4(v) v.x &= km; v.y &= km; v.z &= km; v.w &= km
      MASK4(h0); MASK4(h1); MASK4(h2); MASK4(h3);
      MASK4(h4); MASK4(h5); MASK4(h6); MASK4(h7);
#undef MASK4
      f32x4 acc0 = xacc[t & 1][mt][lane][0];
      f32x4 acc1 = xacc[t & 1][mt][lane][1];
#define HM(v, m) \
      acc0 = __builtin_amdgcn_mfma_f32_16x16x32_bf16(__builtin_bit_cast(bfrag8, v), WFRAG(1, m, 0), acc0, 0, 0, 0); \
      acc1 = __builtin_amdgcn_mfma_f32_16x16x32_bf16(__builtin_bit_cast(bfrag8, v), WFRAG(1, m, 1), acc1, 0, 0, 0)
      HM(h0, 0); HM(h1, 1); HM(h2, 2); HM(h3, 3);
      HM(h4, 4); HM(h5, 5); HM(h6, 6); HM(h7, 7);
#undef HM
      // gate exchange: partner lane (c^8) holds the other two gates
      f32x4 po0, po1;
#pragma unroll
      for (int r = 0; r < 4; ++r) {
        po0[r] = __shfl_xor(acc0[r], 8);
        po1[r] = __shfl_xor(acc1[r], 8);
      }
      float iA, iB, fA, fB, gA, gB, oA, oB;
      if (selhi == 0) {
        iA = acc0[0]; iB = acc0[1]; gA = acc1[0]; gB = acc1[1];
        fA = po0[0];  fB = po0[1];  oA = po1[0];  oB = po1[1];
      } else {
        fA = acc0[2]; fB = acc0[3]; oA = acc1[2]; oB = acc1[3];
        iA = po0[2];  iB = po0[3];  gA = po1[2];  gB = po1[3];
      }
      unsigned short* hbw = hb + (t & 3) * (ROWS * H_);
      {
        float ig = sigm(iA + bi), fg = sigm(fA + bf);
        float gg = tanh_f(gA + bg), og = sigm(oA + bo);
        float rm = iiPA ? 0.f : 1.f;
        cregA = fg * (cregA * rm) + ig * gg;
        st_sys_u16(hbw + rowA * H_ + jcol, (unsigned int)f2bf(og * tanh_f(cregA)));
      }
      {
        float ig = sigm(iB + bi), fg = sigm(fB + bf);
        float gg = tanh_f(gB + bg), og = sigm(oB + bo);
        float rm = iiPB ? 0.f : 1.f;
        cregB = fg * (cregB * rm) + ig * gg;
        st_sys_u16(hbw + rowB * H_ + jcol, (unsigned int)f2bf(og * tanh_f(cregB)));
      }
      drain_vm();
    } else {
      // ---- helpers: xacc(t+1) + LN(t-1) ----
      if (t + 1 < T_) {
        f32x4 a0 = {0.f, 0.f, 0.f, 0.f}, a1 = {0.f, 0.f, 0.f, 0.f};
#pragma unroll
        for (int m = 0; m < 8; ++m) {
          a0 = __builtin_amdgcn_mfma_f32_16x16x32_bf16(xf[m], WFRAG(0, m, 0), a0, 0, 0, 0);
          a1 = __builtin_amdgcn_mfma_f32_16x16x32_bf16(xf[m], WFRAG(0, m, 1), a1, 0, 0, 0);
        }
        xacc[(t + 1) & 1][mt][lane][0] = a0;
        xacc[(t + 1) & 1][mt][lane][1] = a1;
      }
      if (t > 0 && wv < 6) {  // LN(t-1) + x skip, rows 2*mem, 2*mem+1
        int lr = 2 * mem + (wv - 4);
        int gr = rowbase + lr;
        uint2 hv = ld_sys_8B(hbr + lr * H_ + lane * 4);
        float h0v = bf2f((unsigned short)(hv.x & 0xffff));
        float h1v = bf2f((unsigned short)(hv.x >> 16));
        float h2v = bf2f((unsigned short)(hv.y & 0xffff));
        float h3v = bf2f((unsigned short)(hv.y >> 16));
        float s = h0v + h1v + h2v + h3v;
        float q = h0v * h0v + h1v * h1v + h2v * h2v + h3v * h3v;
#pragma unroll
        for (int m = 1; m < 64; m <<= 1) {
          s += __shfl_xor(s, m);
          q += __shfl_xor(q, m);
        }
        float mu = s * (1.0f / 256.0f);
        float var = q * (1.0f / 256.0f) - mu * mu;
        float rs = rsqrtf(var + 1e-5f);
        float4 o4;
        o4.x = (h0v - mu) * rs * lnw4.x + lnb4.x + xskip.x;
        o4.y = (h1v - mu) * rs * lnw4.y + lnb4.y + xskip.y;
        o4.z = (h2v - mu) * rs * lnw4.z + lnb4.z + xskip.z;
        o4.w = (h3v - mu) * rs * lnw4.w + lnb4.w + xskip.w;
        *reinterpret_cast<float4*>(out + ((size_t)gr * T_ + (t - 1)) * H_ + lane * 4) = o4;
      }
    }
    __syncthreads();  // S2: all recurrence stores drained block-wide
    if (tid == 0) arriveN(&myshard[t + 1], 1);  // atomic arrival (R10-proven)
  }

  // ---- epilogue ----
  if (wv == 0) poll_all(T_);
  __syncthreads();
  const unsigned short* hT = hb + ((T_ - 1) & 3) * (ROWS * H_);
  // LN for timestep T-1 (proven R6/R9/R10 path)
  if (wv < 2) {
    int lr = 2 * mem + wv;
    int gr = rowbase + lr;
    uint2 hv = ld_sys_8B(hT + lr * H_ + lane * 4);
    float h0v = bf2f((unsigned short)(hv.x & 0xffff));
    float h1v = bf2f((unsigned short)(hv.x >> 16));
    float h2v = bf2f((unsigned short)(hv.y & 0xffff));
    float h3v = bf2f((unsigned short)(hv.y >> 16));
    float s = h0v + h1v + h2v + h3v;
    float q = h0v * h0v + h1v * h1v + h2v * h2v + h3v * h3v;
#pragma unroll
    for (int m = 1; m < 64; m <<= 1) {
      s += __shfl_xor(s, m);
      q += __shfl_xor(q, m);
    }
    float mu = s * (1.0f / 256.0f);
    float var = q * (1.0f / 256.0f) - mu * mu;
    float rs = rsqrtf(var + 1e-5f);
    const float* xp = x + ((size_t)gr * T_ + (T_ - 1)) * I_ + lane * 4;
    float4 xv = *reinterpret_cast<const float4*>(xp);
    float4 o4;
    o4.x = (h0v - mu) * rs * lnw4.x + lnb4.x + xv.x;
    o4.y = (h1v - mu) * rs * lnw4.y + lnb4.y + xv.y;
    o4.z = (h2v - mu) * rs * lnw4.z + lnb4.z + xv.z;
    o4.w = (h3v - mu) * rs * lnw4.w + lnb4.w + xv.w;
    *reinterpret_cast<float4*>(out + ((size_t)gr * T_ + (T_ - 1)) * H_ + lane * 4) = o4;
  }
  if (wv < 4) {  // final cell state
    st_sys_u32(reinterpret_cast<unsigned int*>(
                   cts + (size_t)(rowbase + rowA) * H_ + jcol),
               __float_as_uint(cregA));
    st_sys_u32(reinterpret_cast<unsigned int*>(
                   cts + (size_t)(rowbase + rowB) * H_ + jcol),
               __float_as_uint(cregB));
  }
  drain_vm();
  __syncthreads();
  if (tid == 0) arriveN(&myshard[T_ + 1], 1);  // cts drained
  if (wv == 0) poll_all(T_ + 1);
  __syncthreads();
  {  // broadcast hT, cT over the T axis (own 2 rows; coalesced writes)
    int r = tid >> 8;
    int lr = 2 * mem + r;
    int gr = rowbase + lr;
    int c4 = (tid & 63) * 4;
    int tph = (tid >> 6) & 3;
    uint2 hu = ld_sys_8B(hT + lr * H_ + c4);
    float4 hv;
    hv.x = bf2f((unsigned short)(hu.x & 0xffff));
    hv.y = bf2f((unsigned short)(hu.x >> 16));
    hv.z = bf2f((unsigned short)(hu.y & 0xffff));
    hv.w = bf2f((unsigned short)(hu.y >> 16));
    uint2 ca = ld_sys_8B(cts + (size_t)gr * H_ + c4);
    uint2 cb = ld_sys_8B(cts + (size_t)gr * H_ + c4 + 2);
    float4 cv;
    cv.x = __uint_as_float(ca.x); cv.y = __uint_as_float(ca.y);
    cv.z = __uint_as_float(cb.x); cv.w = __uint_as_float(cb.y);
    float* o1 = out + (size_t)B_ * T_ * H_ + (size_t)gr * T_ * H_;
    float* o2 = o1 + (size_t)B_ * T_ * H_;
    for (int tt = tph; tt < T_; tt += 4) {
      *reinterpret_cast<float4*>(o1 + tt * H_ + c4) = hv;
      *reinterpret_cast<float4*>(o2 + tt * H_ + c4) = cv;
    }
  }
#undef WFRAG
}

extern "C" void kernel_launch(void* const* d_in, const int* in_sizes, int n_in,
                              void* d_out, int out_size, void* d_ws, size_t ws_size,
                              hipStream_t stream) {
  (void)in_sizes; (void)n_in; (void)out_size; (void)ws_size;
  const float* x = (const float*)d_in[0];
  const int* is_init = (const int*)d_in[1];
  const float* hx = (const float*)d_in[2];
  const float* cx = (const float*)d_in[3];
  const float* W_ih = (const float*)d_in[4];
  const float* W_hh = (const float*)d_in[5];
  const float* b_ih = (const float*)d_in[6];
  const float* b_hh = (const float*)d_in[7];
  const float* ln_w = (const float*)d_in[8];
  const float* ln_b = (const float*)d_in[9];
  float* out = (float*)d_out;

  char* ws = (char*)d_ws;
  unsigned short* hbuf = (unsigned short*)ws;          // 1 MB
  float* cts = (float*)(ws + (1 << 20));               // 512 KB
  int* cnt = (int*)(ws + (1 << 20) + (512 << 10));     // 8g * 8sh * 520 ints = 133 KB

  // x_bf inside each group's OWN o2 output slice (16 MB stride; first 8 MB).
  unsigned short* x_bf = (unsigned short*)(out + 2ull * B_ * T_ * H_);

  cvt_x_group<<<dim3(B_), dim3(256), 0, stream>>>(x, x_bf);
  hipMemsetAsync(cnt, 0, GROUPS * NSH * SHST * sizeof(int), stream);
  // ~49 KB static LDS + 80 KB pad -> 1 block/CU, 256 blocks resident.
  lstm_fused<<<dim3(GROUPS * BPG), dim3(NTHR), 81920, stream>>>(
      x, x_bf, is_init, hx, cx, W_ih, W_hh, b_ih, b_hh, ln_w, ln_b, out,
      hbuf, cts, cnt);
}